// Round 10
// baseline (345.965 us; speedup 1.0000x reference)
//
#include <hip/hip_runtime.h>

#define N_PTS 131072
#define TD 4096
#define DD 64
#define KK 1024
#define MARGIN_TH 2e-3f
#define BPAD 72   // ushorts per code row in LDS (64 + 8 pad = 144 B)

typedef short bf16x8 __attribute__((ext_vector_type(8)));
typedef float f32x4  __attribute__((ext_vector_type(4)));

__device__ inline unsigned short f2bf(float f) {           // RNE float->bf16
    unsigned u = __float_as_uint(f);
    unsigned r = u + 0x7FFFu + ((u >> 16) & 1u);
    return (unsigned short)(r >> 16);
}
__device__ inline float bf2f(unsigned short h) {
    return __uint_as_float(((unsigned)h) << 16);
}

// ---------------- K0: transpose z -> z_hi/z_lo bf16 [N,D]; tail blocks prep emb ----------------
__global__ __launch_bounds__(256) void vq_prep(const float* __restrict__ z,
                                               const float* __restrict__ emb,
                                               unsigned short* __restrict__ zh,
                                               unsigned short* __restrict__ zl,
                                               unsigned short* __restrict__ eh,
                                               unsigned short* __restrict__ el,
                                               float* __restrict__ halfnorm)
{
    __shared__ float tile[64][65];
    const int tid = threadIdx.x;

    if (blockIdx.x >= 2048) {   // ---- eprep: emb -> e_hi/e_lo + fp64 half norms ----
        const int k = (blockIdx.x - 2048) * 256 + tid;
        const float* e = emb + (size_t)k * DD;
        double s = 0.0;
#pragma unroll
        for (int d = 0; d < DD; ++d) {
            const float v = e[d];
            const double dv = (double)v;
            s = fma(dv, dv, s);
            const unsigned short h = f2bf(v);
            eh[(size_t)k * DD + d] = h;
            el[(size_t)k * DD + d] = f2bf(v - bf2f(h));
        }
        halfnorm[k] = (float)(0.5 * s);
        return;
    }

    const int b = blockIdx.x >> 6;
    const int t0 = (blockIdx.x & 63) * 64;

    const int d = tid >> 2, tq = tid & 3;
#pragma unroll
    for (int it = 0; it < 4; ++it) {
        const int tt = tq * 16 + it * 4;
        const float4 v = *(const float4*)(z + ((size_t)b * DD + d) * TD + t0 + tt);
        tile[d][tt] = v.x; tile[d][tt + 1] = v.y; tile[d][tt + 2] = v.z; tile[d][tt + 3] = v.w;
    }
    __syncthreads();

    const int p = tid >> 2, dg = tid & 3;
    bf16x8 h0, h1, l0, l1;
#pragma unroll
    for (int j = 0; j < 8; ++j) {
        const float v0 = tile[dg * 16 + j][p];
        const unsigned short a = f2bf(v0);
        h0[j] = (short)a; l0[j] = (short)f2bf(v0 - bf2f(a));
        const float v1 = tile[dg * 16 + 8 + j][p];
        const unsigned short c = f2bf(v1);
        h1[j] = (short)c; l1[j] = (short)f2bf(v1 - bf2f(c));
    }
    const size_t o = ((size_t)(b * TD + t0 + p)) * DD + dg * 16;
    *(bf16x8*)(zh + o) = h0;
    *(bf16x8*)(zh + o + 8) = h1;
    *(bf16x8*)(zl + o) = l0;
    *(bf16x8*)(zl + o + 8) = l1;
}

// ---------------- K1: MFMA screen + in-wave fp64 rescan + fused hist ----------------
__global__ __launch_bounds__(512, 2) void vq_screen_mfma(
    const unsigned short* __restrict__ zh, const unsigned short* __restrict__ zl,
    const unsigned short* __restrict__ eh, const unsigned short* __restrict__ el,
    const float* __restrict__ hn,
    const float* __restrict__ z, const float* __restrict__ emb,
    int* __restrict__ idx_ws, float* __restrict__ ind_out, int* __restrict__ hist)
{
    __shared__ __align__(16) unsigned short ehs[2][16 * BPAD];
    __shared__ __align__(16) unsigned short els[2][16 * BPAD];
    __shared__ float hns[2][16];
    __shared__ float zsf[8][DD];

    const int tid = threadIdx.x;
    const int lane = tid & 63;
    const int wid = tid >> 6;                 // 0..7
    const int quad = lane >> 4;
    const int col = lane & 15;
    const int pbase = blockIdx.x * 256 + wid * 32;   // 32 points per wave

    const bf16x8* pA0h = (const bf16x8*)(zh + (size_t)(pbase + col) * DD + quad * 8);
    const bf16x8* pA0l = (const bf16x8*)(zl + (size_t)(pbase + col) * DD + quad * 8);
    const bf16x8* pA1h = (const bf16x8*)(zh + (size_t)(pbase + 16 + col) * DD + quad * 8);
    const bf16x8* pA1l = (const bf16x8*)(zl + (size_t)(pbase + 16 + col) * DD + quad * 8);
    const bf16x8 A0h0 = pA0h[0], A0h1 = pA0h[4];
    const bf16x8 A0l0 = pA0l[0], A0l1 = pA0l[4];
    const bf16x8 A1h0 = pA1h[0], A1h1 = pA1h[4];
    const bf16x8 A1l0 = pA1l[0], A1l1 = pA1l[4];

    // staging roles: tid<128 -> eh, 128..255 -> el; tid>=256 idle for staging
    const int sidx = tid & 127;
    const int scode = sidx >> 3;
    const int schunk = sidx & 7;
    const bool shi = (tid < 128);
    const bool stg = (tid < 256);
    const unsigned short* sgl = shi ? eh : el;
    const int soff = scode * BPAD + schunk * 8;

    if (stg) {
        const bf16x8 r = *(const bf16x8*)(sgl + (size_t)scode * DD + schunk * 8);
        *(bf16x8*)((shi ? &ehs[0][0] : &els[0][0]) + soff) = r;
    }
    if (tid < 16) hns[0][tid] = hn[tid];
    __syncthreads();

    float best0[4]  = {1e30f, 1e30f, 1e30f, 1e30f};
    float best20[4] = {1e30f, 1e30f, 1e30f, 1e30f};
    int   bidx0[4]  = {0, 0, 0, 0};
    float best1[4]  = {1e30f, 1e30f, 1e30f, 1e30f};
    float best21[4] = {1e30f, 1e30f, 1e30f, 1e30f};
    int   bidx1[4]  = {0, 0, 0, 0};

    for (int t = 0; t < KK / 16; ++t) {
        const int cur = t & 1;

        bf16x8 nr;
        float nh = 0.f;
        if (t < 63 && stg)
            nr = *(const bf16x8*)(sgl + (size_t)((t + 1) * 16 + scode) * DD + schunk * 8);
        if (t < 63 && tid < 16) nh = hn[(t + 1) * 16 + tid];

        const unsigned short* bh = &ehs[cur][col * BPAD + quad * 8];
        const unsigned short* bl = &els[cur][col * BPAD + quad * 8];
        const bf16x8 Bh0 = *(const bf16x8*)(bh);
        const bf16x8 Bh1 = *(const bf16x8*)(bh + 32);
        const bf16x8 Bl0 = *(const bf16x8*)(bl);
        const bf16x8 Bl1 = *(const bf16x8*)(bl + 32);
        const float hnv = hns[cur][col];

        if (t < 63 && stg)
            *(bf16x8*)((shi ? &ehs[cur ^ 1][0] : &els[cur ^ 1][0]) + soff) = nr;
        if (t < 63 && tid < 16) hns[cur ^ 1][tid] = nh;

        f32x4 p0 = {0.f, 0.f, 0.f, 0.f}, q0 = {0.f, 0.f, 0.f, 0.f};
        f32x4 p1 = {0.f, 0.f, 0.f, 0.f}, q1 = {0.f, 0.f, 0.f, 0.f};
        p0 = __builtin_amdgcn_mfma_f32_16x16x32_bf16(A0h0, Bh0, p0, 0, 0, 0);
        p1 = __builtin_amdgcn_mfma_f32_16x16x32_bf16(A1h0, Bh0, p1, 0, 0, 0);
        q0 = __builtin_amdgcn_mfma_f32_16x16x32_bf16(A0l0, Bh0, q0, 0, 0, 0);
        q1 = __builtin_amdgcn_mfma_f32_16x16x32_bf16(A1l0, Bh0, q1, 0, 0, 0);
        p0 = __builtin_amdgcn_mfma_f32_16x16x32_bf16(A0h1, Bh1, p0, 0, 0, 0);
        p1 = __builtin_amdgcn_mfma_f32_16x16x32_bf16(A1h1, Bh1, p1, 0, 0, 0);
        q0 = __builtin_amdgcn_mfma_f32_16x16x32_bf16(A0l1, Bh1, q0, 0, 0, 0);
        q1 = __builtin_amdgcn_mfma_f32_16x16x32_bf16(A1l1, Bh1, q1, 0, 0, 0);
        p0 = __builtin_amdgcn_mfma_f32_16x16x32_bf16(A0h0, Bl0, p0, 0, 0, 0);
        p1 = __builtin_amdgcn_mfma_f32_16x16x32_bf16(A1h0, Bl0, p1, 0, 0, 0);
        q0 = __builtin_amdgcn_mfma_f32_16x16x32_bf16(A0h1, Bl1, q0, 0, 0, 0);
        q1 = __builtin_amdgcn_mfma_f32_16x16x32_bf16(A1h1, Bl1, q1, 0, 0, 0);

        const int code = t * 16 + col;
#pragma unroll
        for (int r = 0; r < 4; ++r) {
            const float s0 = hnv - (p0[r] + q0[r]);
            const bool l0 = s0 < best0[r];
            best20[r] = fminf(best20[r], fmaxf(best0[r], s0));
            best0[r] = l0 ? s0 : best0[r];
            bidx0[r] = l0 ? code : bidx0[r];
            const float s1 = hnv - (p1[r] + q1[r]);
            const bool l1 = s1 < best1[r];
            best21[r] = fminf(best21[r], fmaxf(best1[r], s1));
            best1[r] = l1 ? s1 : best1[r];
            bidx1[r] = l1 ? code : bidx1[r];
        }

        __syncthreads();
    }

    // merge across 16 cols of each quad-group
#pragma unroll
    for (int off = 1; off < 16; off <<= 1) {
#pragma unroll
        for (int r = 0; r < 4; ++r) {
            {
                const float ob  = __shfl_xor(best0[r],  off, 64);
                const float ob2 = __shfl_xor(best20[r], off, 64);
                const int   oi  = __shfl_xor(bidx0[r],  off, 64);
                const float nb2 = fminf(fminf(best20[r], ob2), fmaxf(best0[r], ob));
                if (ob < best0[r]) { best0[r] = ob; bidx0[r] = oi; }
                best20[r] = nb2;
            }
            {
                const float ob  = __shfl_xor(best1[r],  off, 64);
                const float ob2 = __shfl_xor(best21[r], off, 64);
                const int   oi  = __shfl_xor(bidx1[r],  off, 64);
                const float nb2 = fminf(fminf(best21[r], ob2), fmaxf(best1[r], ob));
                if (ob < best1[r]) { best1[r] = ob; bidx1[r] = oi; }
                best21[r] = nb2;
            }
        }
    }

    // flag mask over the wave's 32 points; write non-flagged results now
    unsigned mflag = 0;
    if (col == 0) {
#pragma unroll
        for (int r = 0; r < 4; ++r) {
            if (best20[r] - best0[r] < MARGIN_TH) mflag |= 1u << (quad * 4 + r);
            else {
                const int n0 = pbase + quad * 4 + r;
                idx_ws[n0] = bidx0[r];
                ind_out[n0] = (float)bidx0[r];
                atomicAdd(&hist[bidx0[r]], 1);
            }
            if (best21[r] - best1[r] < MARGIN_TH) mflag |= 1u << (16 + quad * 4 + r);
            else {
                const int n1 = pbase + 16 + quad * 4 + r;
                idx_ws[n1] = bidx1[r];
                ind_out[n1] = (float)bidx1[r];
                atomicAdd(&hist[bidx1[r]], 1);
            }
        }
    }
    mflag |= __shfl_xor(mflag, 16, 64);
    mflag |= __shfl_xor(mflag, 32, 64);
    mflag = __shfl(mflag, 0, 64);

    // in-wave fp64 exact rescan of flagged points (numpy-exact argmin)
    while (mflag) {
        const int s = __ffs(mflag) - 1;
        mflag &= mflag - 1;
        const int pt = pbase + (s & 16) + (s & 15);
        const int b = pt >> 12, tt = pt & 4095;
        zsf[wid][lane] = z[((size_t)b * DD + lane) * TD + tt];
        __builtin_amdgcn_s_waitcnt(0);
        double best = 1e300;
        int bi = KK;
        for (int kc = 0; kc < KK / 64; ++kc) {
            const int k = kc * 64 + lane;
            const float4* e = (const float4*)(emb + (size_t)k * DD);
            double dot = 0.0, nn = 0.0;
#pragma unroll
            for (int j = 0; j < 16; ++j) {
                float4 ev = e[j];
                double e0 = (double)ev.x, e1 = (double)ev.y, e2 = (double)ev.z, e3 = (double)ev.w;
                nn = fma(e0, e0, fma(e1, e1, fma(e2, e2, fma(e3, e3, nn))));
                dot = fma((double)zsf[wid][4 * j + 0], e0,
                      fma((double)zsf[wid][4 * j + 1], e1,
                      fma((double)zsf[wid][4 * j + 2], e2,
                      fma((double)zsf[wid][4 * j + 3], e3, dot))));
            }
            double sc = 0.5 * nn - dot;
            if (sc < best || (sc == best && k < bi)) { best = sc; bi = k; }
        }
        for (int off = 32; off > 0; off >>= 1) {
            double os = __shfl_down(best, off, 64);
            int oi = __shfl_down(bi, off, 64);
            if (os < best || (os == best && oi < bi)) { best = os; bi = oi; }
        }
        if (lane == 0) {
            idx_ws[pt] = bi;
            ind_out[pt] = (float)bi;
            atomicAdd(&hist[bi], 1);
        }
    }
}

// ---------------- K2: exclusive scan -> cursor, Laplace smoothing -> rsmo ----------------
__global__ __launch_bounds__(1024) void vq_prefix_smo(
    const int* __restrict__ hist, const float* __restrict__ cs,
    int* __restrict__ cursor, float* __restrict__ rsmo)
{
    __shared__ int tmp[KK];
    __shared__ double dred[KK];
    const int k = threadIdx.x;
    const int c = hist[k];
    tmp[k] = c;
    const double ncs = 0.99 * (double)cs[k] + 0.01 * (double)c;
    dred[k] = ncs;
    __syncthreads();
    for (int off = 1; off < KK; off <<= 1) {
        int u = (k >= off) ? tmp[k - off] : 0;
        __syncthreads();
        tmp[k] += u;
        __syncthreads();
    }
    cursor[k] = tmp[k] - c;  // exclusive
    for (int s = 512; s > 0; s >>= 1) {
        if (k < s) dred[k] += dred[k + s];
        __syncthreads();
    }
    const double nsum = dred[0];
    const double smo = (ncs + 1e-5) / (nsum + (double)KK * 1e-5) * nsum;
    rsmo[k] = (float)(1.0 / smo);
}

// ---------------- K3: scatter point ids into per-code lists ----------------
__global__ __launch_bounds__(256) void vq_scatter(const int* __restrict__ idx_ws,
                                                  int* __restrict__ cursor, int* __restrict__ order)
{
    const int n = blockIdx.x * 256 + threadIdx.x;
    const int bi = idx_ws[n];
    const int pos = atomicAdd(&cursor[bi], 1);
    order[pos] = n;
}

// ---------------- K4: balanced segment sum: 64 sorted positions per wave ----------------
__global__ __launch_bounds__(256) void vq_esum2(
    const unsigned short* __restrict__ zh, const unsigned short* __restrict__ zl,
    const int* __restrict__ idx_ws, const int* __restrict__ order,
    float* __restrict__ esum)
{
    const int tid = threadIdx.x;
    const int lane = tid & 63;
    const int w = tid >> 6;
    const int base = blockIdx.x * 256 + w * 64;

    const int pid_l = order[base + lane];
    const int code_l = idx_ws[pid_l];

    float v[64];
#pragma unroll
    for (int j = 0; j < 64; ++j) {
        const int pj = __shfl(pid_l, j, 64);
        const size_t o = (size_t)pj * DD + lane;
        v[j] = bf2f(zh[o]) + bf2f(zl[o]);
    }

    float racc = 0.f;
    int cur = __shfl(code_l, 0, 64);
#pragma unroll
    for (int j = 0; j < 64; ++j) {
        const int cj = __shfl(code_l, j, 64);
        if (cj != cur) {
            atomicAdd(&esum[(size_t)cur * DD + lane], racc);
            racc = 0.f;
            cur = cj;
        }
        racc += v[j];
    }
    atomicAdd(&esum[(size_t)cur * DD + lane], racc);
}

// ---------------- K5: gather z_q (newE inline) + commitment loss + finalize ----------------
__global__ __launch_bounds__(256) void vq_gather_loss(
    const float* __restrict__ z, const float* __restrict__ avg,
    const float* __restrict__ esum, const float* __restrict__ rsmo,
    const int* __restrict__ idx_ws, float* __restrict__ zq_out,
    double* __restrict__ loss_acc, int* __restrict__ done_cnt,
    float* __restrict__ loss_out)
{
    const int tid = threadIdx.x;
    const int n = blockIdx.x * 256 + tid;
    const int b = n >> 12;
    const int t = n & 4095;
    const float* zb = z + ((size_t)b * DD) * TD + t;
    float* ob = zq_out + ((size_t)b * DD) * TD + t;
    const int bi = idx_ws[n];
    const double rs = (double)rsmo[bi];
    const float* av = avg + (size_t)bi * DD;
    const float* es = esum + (size_t)bi * DD;
    double acc = 0.0;
#pragma unroll
    for (int d = 0; d < DD; ++d) {
        const float q = (float)((0.99 * (double)av[d] + 0.01 * (double)es[d]) * rs);
        const float zv = zb[(size_t)d * TD];
        ob[(size_t)d * TD] = q;
        const float df = zv - q;
        acc = fma((double)df, (double)df, acc);
    }
    for (int off = 32; off > 0; off >>= 1) acc += __shfl_down(acc, off, 64);
    __shared__ double wsum[4];
    const int wid = tid >> 6, lane = tid & 63;
    if (lane == 0) wsum[wid] = acc;
    __syncthreads();
    if (tid == 0) {
        atomicAdd(loss_acc, wsum[0] + wsum[1] + wsum[2] + wsum[3]);
        __threadfence();
        const int prev = atomicAdd(done_cnt, 1);
        if (prev == gridDim.x - 1) {
            __threadfence();
            *loss_out = (float)(0.25 * (*loss_acc) / (double)(N_PTS * DD));
        }
    }
}

extern "C" void kernel_launch(void* const* d_in, const int* in_sizes, int n_in,
                              void* d_out, int out_size, void* d_ws, size_t ws_size,
                              hipStream_t stream) {
    const float* z    = (const float*)d_in[0];   // [32, 64, 4096]
    const float* emb  = (const float*)d_in[1];   // [1024, 64]
    const float* cs   = (const float*)d_in[2];   // [1024]
    const float* avg  = (const float*)d_in[3];   // [1024, 64]

    float* out      = (float*)d_out;
    float* zq_out   = out;                // 8388608 floats (32 MiB)
    float* loss_out = out + 8388608;      // 1
    float* ind_out  = out + 8388609;      // 131072 (indices as float)

    // z_hi/z_lo bf16 [N][D] exactly fill the z_q region (dead before K5 rewrites it)
    unsigned short* zh = (unsigned short*)d_out;                       // 16 MiB
    unsigned short* zl = (unsigned short*)((char*)d_out + 16777216);   // 16 MiB

    char* ws = (char*)d_ws;
    int*            idx_ws   = (int*)ws;                     // 512 KB @ 0
    float*          esum     = (float*)(ws + 786432);        // 256 KB [memset]
    int*            hist     = (int*)(ws + 1048576);         // 4 KB   [memset]
    int*            done_cnt = (int*)(ws + 1052676);         // 4 B    [memset]
    double*         loss_acc = (double*)(ws + 1052680);      // 8 B    [memset]
    float*          halfnorm = (float*)(ws + 1052688);       // 4 KB
    int*            cursor   = (int*)(ws + 1056784);         // 4 KB
    int*            order    = (int*)(ws + 1585168);         // 512 KB
    unsigned short* eh       = (unsigned short*)(ws + 2109456); // 128 KB
    unsigned short* el       = (unsigned short*)(ws + 2240528); // 128 KB
    float*          rsmo     = (float*)(ws + 2371600);       // 4 KB

    // zero esum + hist + done_cnt + loss_acc
    hipMemsetAsync(ws + 786432, 0, 266256, stream);

    vq_prep<<<2052, 256, 0, stream>>>(z, emb, zh, zl, eh, el, halfnorm);
    vq_screen_mfma<<<512, 512, 0, stream>>>(zh, zl, eh, el, halfnorm, z, emb,
                                            idx_ws, ind_out, hist);
    vq_prefix_smo<<<1, 1024, 0, stream>>>(hist, cs, cursor, rsmo);
    vq_scatter<<<N_PTS / 256, 256, 0, stream>>>(idx_ws, cursor, order);
    vq_esum2<<<N_PTS / 256, 256, 0, stream>>>(zh, zl, idx_ws, order, esum);
    vq_gather_loss<<<N_PTS / 256, 256, 0, stream>>>(z, avg, esum, rsmo, idx_ws, zq_out,
                                                    loss_acc, done_cnt, loss_out);
}